// Round 23
// baseline (50.217 us; speedup 1.0000x reference)
//
#include <hip/hip_runtime.h>

#define WIN   11
#define IW    512
#define IH    512
#define OW    502         // 512 - 10
#define OH    502
#define NCH   48          // 16*3 channel-images
#define TW    54          // output columns per wave-tile
#define SWC   64          // columns computed in V: TW + 10 = one col per lane
#define SWP   66          // LDS row stride in v2f units (H reads to col 65)
#define CH    8           // chunk height (output rows per chunk)
#define NCHUNK 4          // chunks per slab
#define SLABH (CH*NCHUNK) // 32 output rows per wave
#define NGX   10          // ceil(502/54)
#define NGY   16          // ceil(502/32)
#define NGZ   24          // 48 channels / 2 waves per block
#define PXL   7           // output px per lane in H (8 groups x 7 = 56 >= 54)

typedef float v2f __attribute__((ext_vector_type(2)));

__device__ __forceinline__ float fast_rcp(float x) {
    return __builtin_amdgcn_rcpf(x);   // v_rcp_f32, ~1 ulp
}

// Per-wave slab, NO barriers anywhere (R21-validated): same-wave DS ops are
// in-order, and vbuf aliasing pins V-write/H-read program order; the compiler
// emits only counted lgkmcnt waits. Each wave owns a private vbuf region, so
// there is no cross-wave LDS sharing and no need for s_barrier.
template<bool EDGE>
__device__ __forceinline__ void ssim_slab(const float* __restrict__ p1,
                                          const float* __restrict__ p2,
                                          const float (&w)[WIN],
                                          v2f (*vbuf)[CH][SWP],
                                          int x0, int y0, int lane, float& acc)
{
    // ---- V mapping: one column per lane (all 64 lanes dense).
    const int c = lane;                 // 0..63
    int gx = x0 + c;
    if (EDGE) gx = min(gx, IW - 1);

    // 10-row (a,b) register history: input rows y0 .. y0+9
    v2f h[10];
#pragma unroll
    for (int j = 0; j < 10; ++j) {
        int gy = y0 + j; if (EDGE) gy = min(gy, IH - 1);
        const int gidx = gy * IW + gx;
        h[j].x = p1[gidx];
        h[j].y = p2[gidx];
    }

    // ---- H mapping: row rh, x-group gg of 7 px
    const int rh = lane >> 3;           // 0..7
    const int gg = lane & 7;            // 0..7
    const int xs = gg * PXL;            // 0,7,...,49
    const float c1 = 0.0001f;           // (0.01*1.0)^2
    const float c2 = 0.0009f;           // (0.03*1.0)^2

#pragma unroll
    for (int ci = 0; ci < NCHUNK; ++ci) {
        // ---- load this chunk's 8 new input rows (just-in-time batch)
        const int jbase = y0 + 10 + ci * CH;
        v2f n[CH];
#pragma unroll
        for (int j = 0; j < CH; ++j) {
            int gy = jbase + j; if (EDGE) gy = min(gy, IH - 1);
            const int gidx = gy * IW + gx;
            n[j].x = p1[gidx];
            n[j].y = p2[gidx];
        }

        // ---- vertical blur: 18-row window = h[0..9] ++ n[0..7]
        v2f accA[CH], accB[CH];
#pragma unroll
        for (int r = 0; r < CH; ++r) {
            accA[r] = (v2f){0.f, 0.f};
            accB[r] = (v2f){0.f, 0.f};
        }
#pragma unroll
        for (int j = 0; j < CH + 10; ++j) {
            v2f ab = (j < 10) ? h[j] : n[j - 10];
            v2f st;
            st.x = fmaf(ab.x, ab.x, ab.y * ab.y);   // a^2 + b^2
            st.y = ab.x * ab.y;                     // a*b
#pragma unroll
            for (int k = 0; k < WIN; ++k) {
                const int r = j - k;                // compile-time after unroll
                if (r >= 0 && r < CH) {
                    v2f ws; ws.x = w[k]; ws.y = w[k];
                    accA[r] = __builtin_elementwise_fma(ws, ab, accA[r]);
                    accB[r] = __builtin_elementwise_fma(ws, st, accB[r]);
                }
            }
            if (j >= 10) {                          // row j-10 complete
                vbuf[0][j - 10][c] = accA[j - 10];
                vbuf[1][j - 10][c] = accB[j - 10];
            }
        }
        // ---- history shift: keep last 10 window rows
#pragma unroll
        for (int j = 0; j < 10; ++j)
            h[j] = (j < 2) ? h[8 + j] : n[j - 2];

        // (no fence: in-order per-wave DS pipe orders V-writes before H-reads)

        // ---- H phase: blur packed plane-pairs + SSIM (all 64 lanes)
        {
            v2f resA[PXL], resB[PXL];
#pragma unroll
            for (int q = 0; q < 2; ++q) {
                v2f x2[PXL + 10];
                const v2f* src = &vbuf[q][rh][xs];
#pragma unroll
                for (int t = 0; t < PXL + 10; ++t)
                    x2[t] = src[t];
#pragma unroll
                for (int o = 0; o < PXL; ++o) {
                    v2f s = {0.f, 0.f};
#pragma unroll
                    for (int k = 0; k < WIN; ++k) {
                        v2f ws; ws.x = w[k]; ws.y = w[k];
                        s = __builtin_elementwise_fma(ws, x2[o + k], s);
                    }
                    if (q == 0) resA[o] = s; else resB[o] = s;
                }
            }

            const int oy = y0 + ci * CH + rh;
#pragma unroll
            for (int o = 0; o < PXL; ++o) {
                const int tc = xs + o;              // tile-local column 0..55
                bool valid = (tc < TW);
                if (EDGE) valid = valid && (oy < OH) && ((x0 + tc) < OW);
                if (valid) {
                    float m1 = resA[o].x, m2 = resA[o].y;
                    float mu11 = m1 * m1, mu22 = m2 * m2, mu12 = m1 * m2;
                    float sAB = resB[o].x - mu11 - mu22;   // s11 + s22
                    float s12 = resB[o].y - mu12;
                    float num = (2.f * mu12 + c1) * (2.f * s12 + c2);
                    float den = (mu11 + mu22 + c1) * (sAB + c2);
                    acc += num * fast_rcp(den);
                }
            }
        }
        // (no fence: H-reads -> next V-writes WAR is in-order per wave)
    }
}

// Grid: 10 x-tiles, 16 y-slabs, 24 z (2 channels per block); 128-thread blocks
// = 2 INDEPENDENT waves, private 8.4 KB LDS halves, zero cross-wave sync.
// 3840 blocks = 15/CU available -> tests whether the ~10/CU residency cap is
// per-BLOCK (then waves double to ~18-20/CU) or per-WAVE (then no change).
__global__ __launch_bounds__(128, 4)
void ssim_fused_kernel(const float* __restrict__ img1,
                       const float* __restrict__ img2,
                       const float* __restrict__ win,
                       float* __restrict__ partial)
{
    __shared__ __align__(16) v2f vbuf[2][2][CH][SWP];   // 16,896 B (2 waves)
    const int tid  = threadIdx.x;
    const int wid  = tid >> 6;          // wave 0..1
    const int lane = tid & 63;
    const int ch   = blockIdx.z * 2 + wid;
    const int x0 = blockIdx.x * TW;
    const int y0 = blockIdx.y * SLABH;
    const float* __restrict__ p1 = img1 + (size_t)ch * (IW * IH);
    const float* __restrict__ p2 = img2 + (size_t)ch * (IW * IH);

    float w[WIN];
#pragma unroll
    for (int k = 0; k < WIN; ++k) w[k] = win[k];

    float acc = 0.f;
    const bool edge = (blockIdx.x == gridDim.x - 1) || (blockIdx.y == gridDim.y - 1);
    if (edge) ssim_slab<true >(p1, p2, w, vbuf[wid], x0, y0, lane, acc);
    else      ssim_slab<false>(p1, p2, w, vbuf[wid], x0, y0, lane, acc);

    // ---- per-wave reduction; lane 0 of each wave writes its own partial
#pragma unroll
    for (int off = 32; off > 0; off >>= 1)
        acc += __shfl_down(acc, off, 64);
    if (lane == 0) {
        partial[(size_t)ch * (NGX * NGY) + blockIdx.y * NGX + blockIdx.x] = acc;
    }
}

__global__ __launch_bounds__(256)
void reduce_partials_kernel(const float* __restrict__ partial, int n4,
                            float* __restrict__ out, double inv_count)
{
    __shared__ double sd[256];
    const float4* p4 = reinterpret_cast<const float4*>(partial);
    double s = 0.0;
    for (int i = threadIdx.x; i < n4; i += 256) {
        float4 f = p4[i];
        s += (double)f.x + (double)f.y + (double)f.z + (double)f.w;
    }
    sd[threadIdx.x] = s;
    __syncthreads();
    for (int off = 128; off > 0; off >>= 1) {
        if (threadIdx.x < off) sd[threadIdx.x] += sd[threadIdx.x + off];
        __syncthreads();
    }
    if (threadIdx.x == 0)
        out[0] = (float)(sd[0] * inv_count);
}

extern "C" void kernel_launch(void* const* d_in, const int* in_sizes, int n_in,
                              void* d_out, int out_size, void* d_ws, size_t ws_size,
                              hipStream_t stream)
{
    const float* img1 = (const float*)d_in[0];
    const float* img2 = (const float*)d_in[1];
    const float* win  = (const float*)d_in[2];
    float* out = (float*)d_out;
    float* partial = (float*)d_ws;

    dim3 grid(NGX, NGY, NGZ);            // 10 x 16 x 24 = 3840 blocks x 2 waves
    dim3 block(128);

    ssim_fused_kernel<<<grid, block, 0, stream>>>(img1, img2, win, partial);

    const int nparts = NGX * NGY * NCH;  // 7680 wave-partials, divisible by 4
    const double inv_count = 1.0 / ((double)NCH * OW * OH);
    reduce_partials_kernel<<<1, 256, 0, stream>>>(partial, nparts / 4, out, inv_count);
}

// Round 24
// 47.614 us; speedup vs baseline: 1.0547x; 1.0547x over previous
//
#include <hip/hip_runtime.h>

#define WIN   11
#define IW    512
#define IH    512
#define OW    502         // 512 - 10
#define OH    502
#define NCH   48          // 16*3 channel-images
#define TW    54          // output columns per wave-tile
#define SWC   64          // columns computed in V: TW + 10 = one col per lane
#define SWP   66          // LDS row stride in v2f units (H reads to col 65)
#define CH    8           // chunk height (output rows per chunk)
#define NCHUNK 8          // chunks per slab (R22: halo amortization)
#define SLABH (CH*NCHUNK) // 64 output rows per block
#define NGX   10          // ceil(502/54)
#define NGY   8           // ceil(502/64)
#define PXL   7           // output px per lane in H (8 groups x 7 = 56 >= 54)

typedef float v2f __attribute__((ext_vector_type(2)));

__device__ __forceinline__ float fast_rcp(float x) {
    return __builtin_amdgcn_rcpf(x);   // v_rcp_f32, ~1 ulp
}

// Inline-asm LDS read: compiler CANNOT sink this to its use (R19's failure
// mode), so the 34-read H window issues ~1300 cycles before its data is
// needed. "memory" clobber pins ordering vs the C-level ds_writes.
#define DSRD(dst, base, OFF) \
    asm volatile("ds_read_b64 %0, %1 offset:" #OFF \
                 : "=v"(dst) : "v"(base) : "memory")

#define ISSUE17(x, b) \
    DSRD(x[0],  b, 0);   DSRD(x[1],  b, 8);   DSRD(x[2],  b, 16);  \
    DSRD(x[3],  b, 24);  DSRD(x[4],  b, 32);  DSRD(x[5],  b, 40);  \
    DSRD(x[6],  b, 48);  DSRD(x[7],  b, 56);  DSRD(x[8],  b, 64);  \
    DSRD(x[9],  b, 72);  DSRD(x[10], b, 80);  DSRD(x[11], b, 88);  \
    DSRD(x[12], b, 96);  DSRD(x[13], b, 104); DSRD(x[14], b, 112); \
    DSRD(x[15], b, 120); DSRD(x[16], b, 128);

template<bool EDGE>
__device__ __forceinline__ void load_rows(const float* __restrict__ p1,
                                          const float* __restrict__ p2,
                                          int gx, int jbase, v2f (&dst)[CH])
{
#pragma unroll
    for (int j = 0; j < CH; ++j) {
        int gy = jbase + j; if (EDGE) gy = min(gy, IH - 1);
        const int gidx = gy * IW + gx;
        dst[j].x = p1[gidx];
        dst[j].y = p2[gidx];
    }
}

// V pass: 18-row window = h[0..9] ++ n[0..7] -> vbuf rows 0..7; shifts h.
__device__ __forceinline__ void vpass(const float (&w)[WIN],
                                      v2f (&h)[10], const v2f (&n)[CH],
                                      v2f (*vbuf)[CH][SWP], int c)
{
    v2f accA[CH], accB[CH];
#pragma unroll
    for (int r = 0; r < CH; ++r) {
        accA[r] = (v2f){0.f, 0.f};
        accB[r] = (v2f){0.f, 0.f};
    }
#pragma unroll
    for (int j = 0; j < CH + 10; ++j) {
        v2f ab = (j < 10) ? h[j] : n[j - 10];
        v2f st;
        st.x = fmaf(ab.x, ab.x, ab.y * ab.y);   // a^2 + b^2
        st.y = ab.x * ab.y;                     // a*b
#pragma unroll
        for (int k = 0; k < WIN; ++k) {
            const int r = j - k;                // compile-time after unroll
            if (r >= 0 && r < CH) {
                v2f ws; ws.x = w[k]; ws.y = w[k];
                accA[r] = __builtin_elementwise_fma(ws, ab, accA[r]);
                accB[r] = __builtin_elementwise_fma(ws, st, accB[r]);
            }
        }
        if (j >= 10) {                          // row j-10 complete
            vbuf[0][j - 10][c] = accA[j - 10];
            vbuf[1][j - 10][c] = accB[j - 10];
        }
    }
#pragma unroll
    for (int j = 0; j < 10; ++j)
        h[j] = (j < 2) ? h[8 + j] : n[j - 2];
}

// H compute: pure VALU on the asm-loaded window.
template<bool EDGE>
__device__ __forceinline__ void hcompute(const v2f (&xA)[17], const v2f (&xB)[17],
                                         const float (&w)[WIN],
                                         int oy, int x0, int xs, float& acc)
{
    const float c1 = 0.0001f;   // (0.01*1.0)^2
    const float c2 = 0.0009f;   // (0.03*1.0)^2
#pragma unroll
    for (int o = 0; o < PXL; ++o) {
        v2f sA = {0.f, 0.f}, sB = {0.f, 0.f};
#pragma unroll
        for (int k = 0; k < WIN; ++k) {
            v2f ws; ws.x = w[k]; ws.y = w[k];
            sA = __builtin_elementwise_fma(ws, xA[o + k], sA);
            sB = __builtin_elementwise_fma(ws, xB[o + k], sB);
        }
        const int tc = xs + o;                  // tile-local column
        bool valid = (tc < TW);
        if (EDGE) valid = valid && (oy < OH) && ((x0 + tc) < OW);
        if (valid) {
            float m1 = sA.x, m2 = sA.y;
            float mu11 = m1 * m1, mu22 = m2 * m2, mu12 = m1 * m2;
            float sAB = sB.x - mu11 - mu22;     // s11 + s22
            float s12 = sB.y - mu12;
            float num = (2.f * mu12 + c1) * (2.f * s12 + c2);
            float den = (mu11 + mu22 + c1) * (sAB + c2);
            acc += num * fast_rcp(den);
        }
    }
}

// Pipelined slab: Hissue(ci) [asm] -> V(ci+1) [overwrites vbuf; safe: the
// per-wave DS pipe is in-order, so reads issued earlier return old data] ->
// lgkmcnt(0)+sched_barrier -> Hcompute(ci). No __syncthreads anywhere
// (1-wave block; R21-validated correct and fence-free).
template<bool EDGE>
__device__ __forceinline__ void ssim_slab(const float* __restrict__ p1,
                                          const float* __restrict__ p2,
                                          const float (&w)[WIN],
                                          v2f (*vbuf)[CH][SWP],
                                          int x0, int y0, int tid, float& acc)
{
    const int c = tid;                  // 0..63, one column per lane
    int gx = x0 + c;
    if (EDGE) gx = min(gx, IW - 1);

    v2f h[10];
#pragma unroll
    for (int j = 0; j < 10; ++j) {
        int gy = y0 + j; if (EDGE) gy = min(gy, IH - 1);
        const int gidx = gy * IW + gx;
        h[j].x = p1[gidx];
        h[j].y = p2[gidx];
    }
    v2f n[CH];
    load_rows<EDGE>(p1, p2, gx, y0 + 10, n);

    const int rh = tid >> 3;            // 0..7
    const int gg = tid & 7;             // 0..7
    const int xs = gg * PXL;            // 0,7,...,49

    // LDS byte offsets of this lane's H windows (generic LDS addr: low 32
    // bits are the LDS offset on gfx9+).
    const unsigned b0 = (unsigned)(uintptr_t)&vbuf[0][rh][xs];
    const unsigned b1 = (unsigned)(uintptr_t)&vbuf[1][rh][xs];

    vpass(w, h, n, vbuf, c);            // chunk 0 -> vbuf

#pragma unroll
    for (int ci = 0; ci < NCHUNK; ++ci) {
        v2f xA[17], xB[17];
        ISSUE17(xA, b0);                // issue chunk ci's H reads (asm)
        ISSUE17(xB, b1);

        if (ci + 1 < NCHUNK) {          // V(ci+1): ~1300 VALU cycles of cover
            load_rows<EDGE>(p1, p2, gx, y0 + 10 + (ci + 1) * CH, n);
            vpass(w, h, n, vbuf, c);
        }

        asm volatile("s_waitcnt lgkmcnt(0)" ::: "memory");
        __builtin_amdgcn_sched_barrier(0);   // rule #18: pin compute below wait

        hcompute<EDGE>(xA, xB, w, y0 + ci * CH + rh, x0, xs, acc);
    }
}

// Grid: 10 x-tiles, 8 y-slabs, 48 channel-images; 64-thread (1-wave) blocks.
// launch_bounds(64,2): VGPR cap 256 so the 68-VGPR asm window doesn't spill.
__global__ __launch_bounds__(64, 2)
void ssim_fused_kernel(const float* __restrict__ img1,
                       const float* __restrict__ img2,
                       const float* __restrict__ win,
                       float* __restrict__ partial)
{
    __shared__ __align__(16) v2f vbuf[2][CH][SWP];   // 8,448 B
    const int tid = threadIdx.x;
    const int ch = blockIdx.z;
    const int x0 = blockIdx.x * TW;
    const int y0 = blockIdx.y * SLABH;
    const float* __restrict__ p1 = img1 + (size_t)ch * (IW * IH);
    const float* __restrict__ p2 = img2 + (size_t)ch * (IW * IH);

    float w[WIN];
#pragma unroll
    for (int k = 0; k < WIN; ++k) w[k] = win[k];

    float acc = 0.f;
    const bool edge = (blockIdx.x == gridDim.x - 1) || (blockIdx.y == gridDim.y - 1);
    if (edge) ssim_slab<true >(p1, p2, w, vbuf, x0, y0, tid, acc);
    else      ssim_slab<false>(p1, p2, w, vbuf, x0, y0, tid, acc);

    // ---- wave reduction (64 lanes), lane 0 writes the block partial
#pragma unroll
    for (int off = 32; off > 0; off >>= 1)
        acc += __shfl_down(acc, off, 64);
    if (tid == 0) {
        partial[(size_t)blockIdx.z * (gridDim.x * gridDim.y)
                + blockIdx.y * gridDim.x + blockIdx.x] = acc;
    }
}

__global__ __launch_bounds__(256)
void reduce_partials_kernel(const float* __restrict__ partial, int n4,
                            float* __restrict__ out, double inv_count)
{
    __shared__ double sd[256];
    const float4* p4 = reinterpret_cast<const float4*>(partial);
    double s = 0.0;
    for (int i = threadIdx.x; i < n4; i += 256) {
        float4 f = p4[i];
        s += (double)f.x + (double)f.y + (double)f.z + (double)f.w;
    }
    sd[threadIdx.x] = s;
    __syncthreads();
    for (int off = 128; off > 0; off >>= 1) {
        if (threadIdx.x < off) sd[threadIdx.x] += sd[threadIdx.x + off];
        __syncthreads();
    }
    if (threadIdx.x == 0)
        out[0] = (float)(sd[0] * inv_count);
}

extern "C" void kernel_launch(void* const* d_in, const int* in_sizes, int n_in,
                              void* d_out, int out_size, void* d_ws, size_t ws_size,
                              hipStream_t stream)
{
    const float* img1 = (const float*)d_in[0];
    const float* img2 = (const float*)d_in[1];
    const float* win  = (const float*)d_in[2];
    float* out = (float*)d_out;
    float* partial = (float*)d_ws;

    dim3 grid(NGX, NGY, NCH);            // 10 x 8 x 48 = 3840 blocks (1 wave each)
    dim3 block(64);

    ssim_fused_kernel<<<grid, block, 0, stream>>>(img1, img2, win, partial);

    const int nblocks = NGX * NGY * NCH; // 3840, divisible by 4
    const double inv_count = 1.0 / ((double)NCH * OW * OH);
    reduce_partials_kernel<<<1, 256, 0, stream>>>(partial, nblocks / 4, out, inv_count);
}

// Round 25
// 47.567 us; speedup vs baseline: 1.0557x; 1.0010x over previous
//
#include <hip/hip_runtime.h>

#define WIN   11
#define IW    512
#define IH    512
#define OW    502         // 512 - 10
#define OH    502
#define NCH   48          // 16*3 channel-images
#define TW    54          // output columns per wave-tile
#define SWC   64          // columns computed in V: TW + 10 = one col per lane
#define SWP   66          // LDS row stride in v2f units (H reads to col 65)
#define CH    8           // chunk height (output rows per chunk)
#define NCHUNK 8          // chunks per slab (halo amortization, R22)
#define SLABH (CH*NCHUNK) // 64 output rows per block
#define NGX   10          // ceil(502/54)
#define NGY   8           // ceil(502/64)
#define PXL   7           // output px per lane in H (8 groups x 7 = 56 >= 54)

typedef float v2f __attribute__((ext_vector_type(2)));

__device__ __forceinline__ float fast_rcp(float x) {
    return __builtin_amdgcn_rcpf(x);   // v_rcp_f32, ~1 ulp
}

template<bool EDGE>
__device__ __forceinline__ void ssim_slab(const float* __restrict__ p1,
                                          const float* __restrict__ p2,
                                          const float (&w)[WIN],
                                          v2f (*vbuf)[CH][SWP],
                                          int x0, int y0, int tid, float& acc)
{
    // ---- V mapping: one column per lane (all 64 lanes dense).
    const int c = tid;                  // 0..63
    int gx = x0 + c;
    if (EDGE) gx = min(gx, IW - 1);

    // 10-row (a,b) register history: input rows y0 .. y0+9
    v2f h[10];
#pragma unroll
    for (int j = 0; j < 10; ++j) {
        int gy = y0 + j; if (EDGE) gy = min(gy, IH - 1);
        const int gidx = gy * IW + gx;
        h[j].x = p1[gidx];
        h[j].y = p2[gidx];
    }

    // ---- H mapping: row rh, x-group gg of 7 px
    const int rh = tid >> 3;            // 0..7
    const int gg = tid & 7;             // 0..7
    const int xs = gg * PXL;            // 0,7,...,49
    const float c1 = 0.0001f;           // (0.01*1.0)^2
    const float c2 = 0.0009f;           // (0.03*1.0)^2

#pragma unroll
    for (int ci = 0; ci < NCHUNK; ++ci) {
        // ---- load this chunk's 8 new input rows (just-in-time batch)
        const int jbase = y0 + 10 + ci * CH;
        v2f n[CH];
#pragma unroll
        for (int j = 0; j < CH; ++j) {
            int gy = jbase + j; if (EDGE) gy = min(gy, IH - 1);
            const int gidx = gy * IW + gx;
            n[j].x = p1[gidx];
            n[j].y = p2[gidx];
        }

        // ---- vertical blur: 18-row window = h[0..9] ++ n[0..7]
        v2f accA[CH], accB[CH];
#pragma unroll
        for (int r = 0; r < CH; ++r) {
            accA[r] = (v2f){0.f, 0.f};
            accB[r] = (v2f){0.f, 0.f};
        }
#pragma unroll
        for (int j = 0; j < CH + 10; ++j) {
            v2f ab = (j < 10) ? h[j] : n[j - 10];
            v2f st;
            st.x = fmaf(ab.x, ab.x, ab.y * ab.y);   // a^2 + b^2
            st.y = ab.x * ab.y;                     // a*b
#pragma unroll
            for (int k = 0; k < WIN; ++k) {
                const int r = j - k;                // compile-time after unroll
                if (r >= 0 && r < CH) {
                    v2f ws; ws.x = w[k]; ws.y = w[k];
                    accA[r] = __builtin_elementwise_fma(ws, ab, accA[r]);
                    accB[r] = __builtin_elementwise_fma(ws, st, accB[r]);
                }
            }
            if (j >= 10) {                          // row j-10 complete
                vbuf[0][j - 10][c] = accA[j - 10];
                vbuf[1][j - 10][c] = accB[j - 10];
            }
        }
        // ---- history shift: keep last 10 window rows
#pragma unroll
        for (int j = 0; j < 10; ++j)
            h[j] = (j < 2) ? h[8 + j] : n[j - 2];

        __syncthreads();   // 1-wave block: s_barrier elided, lgkm ordering only

        // ---- H phase: blur packed plane-pairs + SSIM (all 64 lanes)
        {
            v2f resA[PXL], resB[PXL];
#pragma unroll
            for (int q = 0; q < 2; ++q) {
                v2f x2[PXL + 10];
                const v2f* src = &vbuf[q][rh][xs];
#pragma unroll
                for (int t = 0; t < PXL + 10; ++t)
                    x2[t] = src[t];
#pragma unroll
                for (int o = 0; o < PXL; ++o) {
                    v2f s = {0.f, 0.f};
#pragma unroll
                    for (int k = 0; k < WIN; ++k) {
                        v2f ws; ws.x = w[k]; ws.y = w[k];
                        s = __builtin_elementwise_fma(ws, x2[o + k], s);
                    }
                    if (q == 0) resA[o] = s; else resB[o] = s;
                }
            }

            const int oy = y0 + ci * CH + rh;
#pragma unroll
            for (int o = 0; o < PXL; ++o) {
                const int tc = xs + o;              // tile-local column 0..55
                bool valid = (tc < TW);
                if (EDGE) valid = valid && (oy < OH) && ((x0 + tc) < OW);
                if (valid) {
                    float m1 = resA[o].x, m2 = resA[o].y;
                    float mu11 = m1 * m1, mu22 = m2 * m2, mu12 = m1 * m2;
                    float sAB = resB[o].x - mu11 - mu22;   // s11 + s22
                    float s12 = resB[o].y - mu12;
                    float num = (2.f * mu12 + c1) * (2.f * s12 + c2);
                    float den = (mu11 + mu22 + c1) * (sAB + c2);
                    acc += num * fast_rcp(den);
                }
            }
        }
        __syncthreads();   // elided barrier; orders H reads before next V writes
    }
}

// Grid: 10 x-tiles, 8 y-slabs, 48 channel-images; 64-thread (1-wave) blocks.
__global__ __launch_bounds__(64, 4)
void ssim_fused_kernel(const float* __restrict__ img1,
                       const float* __restrict__ img2,
                       const float* __restrict__ win,
                       float* __restrict__ partial)
{
    __shared__ __align__(16) v2f vbuf[2][CH][SWP];   // 8,448 B
    const int tid = threadIdx.x;
    const int ch = blockIdx.z;
    const int x0 = blockIdx.x * TW;
    const int y0 = blockIdx.y * SLABH;
    const float* __restrict__ p1 = img1 + (size_t)ch * (IW * IH);
    const float* __restrict__ p2 = img2 + (size_t)ch * (IW * IH);

    float w[WIN];
#pragma unroll
    for (int k = 0; k < WIN; ++k) w[k] = win[k];

    float acc = 0.f;
    const bool edge = (blockIdx.x == gridDim.x - 1) || (blockIdx.y == gridDim.y - 1);
    if (edge) ssim_slab<true >(p1, p2, w, vbuf, x0, y0, tid, acc);
    else      ssim_slab<false>(p1, p2, w, vbuf, x0, y0, tid, acc);

    // ---- wave reduction (64 lanes), lane 0 writes the block partial
#pragma unroll
    for (int off = 32; off > 0; off >>= 1)
        acc += __shfl_down(acc, off, 64);
    if (tid == 0) {
        partial[(size_t)blockIdx.z * (gridDim.x * gridDim.y)
                + blockIdx.y * gridDim.x + blockIdx.x] = acc;
    }
}

__global__ __launch_bounds__(256)
void reduce_partials_kernel(const float* __restrict__ partial, int n4,
                            float* __restrict__ out, double inv_count)
{
    __shared__ double sd[256];
    const float4* p4 = reinterpret_cast<const float4*>(partial);
    double s = 0.0;
    for (int i = threadIdx.x; i < n4; i += 256) {
        float4 f = p4[i];
        s += (double)f.x + (double)f.y + (double)f.z + (double)f.w;
    }
    sd[threadIdx.x] = s;
    __syncthreads();
    for (int off = 128; off > 0; off >>= 1) {
        if (threadIdx.x < off) sd[threadIdx.x] += sd[threadIdx.x + off];
        __syncthreads();
    }
    if (threadIdx.x == 0)
        out[0] = (float)(sd[0] * inv_count);
}

extern "C" void kernel_launch(void* const* d_in, const int* in_sizes, int n_in,
                              void* d_out, int out_size, void* d_ws, size_t ws_size,
                              hipStream_t stream)
{
    const float* img1 = (const float*)d_in[0];
    const float* img2 = (const float*)d_in[1];
    const float* win  = (const float*)d_in[2];
    float* out = (float*)d_out;
    float* partial = (float*)d_ws;

    dim3 grid(NGX, NGY, NCH);            // 10 x 8 x 48 = 3840 blocks (1 wave each)
    dim3 block(64);

    ssim_fused_kernel<<<grid, block, 0, stream>>>(img1, img2, win, partial);

    const int nblocks = NGX * NGY * NCH; // 3840, divisible by 4
    const double inv_count = 1.0 / ((double)NCH * OW * OH);
    reduce_partials_kernel<<<1, 256, 0, stream>>>(partial, nblocks / 4, out, inv_count);
}

// Round 26
// 47.471 us; speedup vs baseline: 1.0578x; 1.0020x over previous
//
#include <hip/hip_runtime.h>

#define WIN   11
#define IW    512
#define IH    512
#define OW    502         // 512 - 10
#define OH    502
#define NCH   48          // 16*3 channel-images
#define TW    54          // output columns per wave-tile
#define SWC   64          // columns computed in V: TW + 10 = one col per lane
#define SWP   66          // LDS row stride in v2f units (H reads to col 65)
#define CH    8           // chunk height (output rows per chunk)
#define NCHUNK 8          // chunks per slab (halo amortization, R22)
#define SLABH (CH*NCHUNK) // 64 output rows per block
#define NGX   10          // ceil(502/54)
#define NGY   8           // ceil(502/64)
#define PXL   7           // output px per lane in H (8 groups x 7 = 56 >= 54)

typedef float v2f __attribute__((ext_vector_type(2)));

__device__ __forceinline__ float fast_rcp(float x) {
    return __builtin_amdgcn_rcpf(x);   // v_rcp_f32, ~1 ulp
}

// Plane-split slab: ONE 4.2 KB LDS buffer, used twice per chunk.
//   V_A -> LDS -> H_A (resA in regs) -> V_B -> LDS -> H_B -> SSIM.
// Halves LDS/wave vs the R22 champion to test the residency=f(LDS/wave)
// theory (R1/R2: ~6 KB/wave -> 17-23 waves/CU; all 8.4 KB configs -> ~10).
// Safe without double-buffering: per-wave DS pipe is in-order, so H_A's
// reads (earlier in program order) return pre-V_B data. 1-wave block:
// __syncthreads costs only the lgkm ordering (s_barrier elided).
template<bool EDGE>
__device__ __forceinline__ void ssim_slab(const float* __restrict__ p1,
                                          const float* __restrict__ p2,
                                          const float (&w)[WIN],
                                          v2f (*vbuf)[SWP],      // [CH][SWP]
                                          int x0, int y0, int tid, float& acc)
{
    // ---- V mapping: one column per lane (all 64 lanes dense).
    const int c = tid;                  // 0..63
    int gx = x0 + c;
    if (EDGE) gx = min(gx, IW - 1);

    // 10-row (a,b) register history: input rows y0 .. y0+9
    v2f h[10];
#pragma unroll
    for (int j = 0; j < 10; ++j) {
        int gy = y0 + j; if (EDGE) gy = min(gy, IH - 1);
        const int gidx = gy * IW + gx;
        h[j].x = p1[gidx];
        h[j].y = p2[gidx];
    }

    // ---- H mapping: row rh, x-group gg of 7 px
    const int rh = tid >> 3;            // 0..7
    const int gg = tid & 7;             // 0..7
    const int xs = gg * PXL;            // 0,7,...,49
    const float c1 = 0.0001f;           // (0.01*1.0)^2
    const float c2 = 0.0009f;           // (0.03*1.0)^2

#pragma unroll
    for (int ci = 0; ci < NCHUNK; ++ci) {
        // ---- load this chunk's 8 new input rows (just-in-time batch)
        const int jbase = y0 + 10 + ci * CH;
        v2f n[CH];
#pragma unroll
        for (int j = 0; j < CH; ++j) {
            int gy = jbase + j; if (EDGE) gy = min(gy, IH - 1);
            const int gidx = gy * IW + gx;
            n[j].x = p1[gidx];
            n[j].y = p2[gidx];
        }

        // ======== pass A: vertical blur of (a, b) -> vbuf ========
        {
            v2f accA[CH];
#pragma unroll
            for (int r = 0; r < CH; ++r) accA[r] = (v2f){0.f, 0.f};
#pragma unroll
            for (int j = 0; j < CH + 10; ++j) {
                v2f ab = (j < 10) ? h[j] : n[j - 10];
#pragma unroll
                for (int k = 0; k < WIN; ++k) {
                    const int r = j - k;            // compile-time after unroll
                    if (r >= 0 && r < CH) {
                        v2f ws; ws.x = w[k]; ws.y = w[k];
                        accA[r] = __builtin_elementwise_fma(ws, ab, accA[r]);
                    }
                }
                if (j >= 10)
                    vbuf[j - 10][c] = accA[j - 10];
            }
        }
        __syncthreads();   // elided s_barrier; lgkm ordering only

        // ---- H_A: horizontal blur of (mu1, mu2) -> resA in registers
        v2f resA[PXL];
        {
            v2f x2[PXL + 10];
            const v2f* src = &vbuf[rh][xs];
#pragma unroll
            for (int t = 0; t < PXL + 10; ++t)
                x2[t] = src[t];
#pragma unroll
            for (int o = 0; o < PXL; ++o) {
                v2f s = {0.f, 0.f};
#pragma unroll
                for (int k = 0; k < WIN; ++k) {
                    v2f ws; ws.x = w[k]; ws.y = w[k];
                    s = __builtin_elementwise_fma(ws, x2[o + k], s);
                }
                resA[o] = s;
            }
        }
        __syncthreads();

        // ======== pass B: vertical blur of (a^2+b^2, ab) -> same vbuf ========
        {
            v2f accB[CH];
#pragma unroll
            for (int r = 0; r < CH; ++r) accB[r] = (v2f){0.f, 0.f};
#pragma unroll
            for (int j = 0; j < CH + 10; ++j) {
                v2f ab = (j < 10) ? h[j] : n[j - 10];
                v2f st;
                st.x = fmaf(ab.x, ab.x, ab.y * ab.y);   // a^2 + b^2
                st.y = ab.x * ab.y;                     // a*b
#pragma unroll
                for (int k = 0; k < WIN; ++k) {
                    const int r = j - k;
                    if (r >= 0 && r < CH) {
                        v2f ws; ws.x = w[k]; ws.y = w[k];
                        accB[r] = __builtin_elementwise_fma(ws, st, accB[r]);
                    }
                }
                if (j >= 10)
                    vbuf[j - 10][c] = accB[j - 10];
            }
        }
        // ---- history shift (after BOTH passes have consumed h)
#pragma unroll
        for (int j = 0; j < 10; ++j)
            h[j] = (j < 2) ? h[8 + j] : n[j - 2];

        __syncthreads();

        // ---- H_B: horizontal blur of second moments + SSIM combine
        {
            v2f x2[PXL + 10];
            const v2f* src = &vbuf[rh][xs];
#pragma unroll
            for (int t = 0; t < PXL + 10; ++t)
                x2[t] = src[t];

            const int oy = y0 + ci * CH + rh;
#pragma unroll
            for (int o = 0; o < PXL; ++o) {
                v2f sB = {0.f, 0.f};
#pragma unroll
                for (int k = 0; k < WIN; ++k) {
                    v2f ws; ws.x = w[k]; ws.y = w[k];
                    sB = __builtin_elementwise_fma(ws, x2[o + k], sB);
                }
                const int tc = xs + o;              // tile-local column 0..55
                bool valid = (tc < TW);
                if (EDGE) valid = valid && (oy < OH) && ((x0 + tc) < OW);
                if (valid) {
                    float m1 = resA[o].x, m2 = resA[o].y;
                    float mu11 = m1 * m1, mu22 = m2 * m2, mu12 = m1 * m2;
                    float sAB = sB.x - mu11 - mu22;   // s11 + s22
                    float s12 = sB.y - mu12;
                    float num = (2.f * mu12 + c1) * (2.f * s12 + c2);
                    float den = (mu11 + mu22 + c1) * (sAB + c2);
                    acc += num * fast_rcp(den);
                }
            }
        }
        __syncthreads();   // orders H_B reads before next chunk's V_A writes
    }
}

// Grid: 10 x-tiles, 8 y-slabs, 48 channel-images; 64-thread (1-wave) blocks.
__global__ __launch_bounds__(64, 4)
void ssim_fused_kernel(const float* __restrict__ img1,
                       const float* __restrict__ img2,
                       const float* __restrict__ win,
                       float* __restrict__ partial)
{
    __shared__ __align__(16) v2f vbuf[CH][SWP];   // 4,224 B (half the champion)
    const int tid = threadIdx.x;
    const int ch = blockIdx.z;
    const int x0 = blockIdx.x * TW;
    const int y0 = blockIdx.y * SLABH;
    const float* __restrict__ p1 = img1 + (size_t)ch * (IW * IH);
    const float* __restrict__ p2 = img2 + (size_t)ch * (IW * IH);

    float w[WIN];
#pragma unroll
    for (int k = 0; k < WIN; ++k) w[k] = win[k];

    float acc = 0.f;
    const bool edge = (blockIdx.x == gridDim.x - 1) || (blockIdx.y == gridDim.y - 1);
    if (edge) ssim_slab<true >(p1, p2, w, vbuf, x0, y0, tid, acc);
    else      ssim_slab<false>(p1, p2, w, vbuf, x0, y0, tid, acc);

    // ---- wave reduction (64 lanes), lane 0 writes the block partial
#pragma unroll
    for (int off = 32; off > 0; off >>= 1)
        acc += __shfl_down(acc, off, 64);
    if (tid == 0) {
        partial[(size_t)blockIdx.z * (gridDim.x * gridDim.y)
                + blockIdx.y * gridDim.x + blockIdx.x] = acc;
    }
}

__global__ __launch_bounds__(256)
void reduce_partials_kernel(const float* __restrict__ partial, int n4,
                            float* __restrict__ out, double inv_count)
{
    __shared__ double sd[256];
    const float4* p4 = reinterpret_cast<const float4*>(partial);
    double s = 0.0;
    for (int i = threadIdx.x; i < n4; i += 256) {
        float4 f = p4[i];
        s += (double)f.x + (double)f.y + (double)f.z + (double)f.w;
    }
    sd[threadIdx.x] = s;
    __syncthreads();
    for (int off = 128; off > 0; off >>= 1) {
        if (threadIdx.x < off) sd[threadIdx.x] += sd[threadIdx.x + off];
        __syncthreads();
    }
    if (threadIdx.x == 0)
        out[0] = (float)(sd[0] * inv_count);
}

extern "C" void kernel_launch(void* const* d_in, const int* in_sizes, int n_in,
                              void* d_out, int out_size, void* d_ws, size_t ws_size,
                              hipStream_t stream)
{
    const float* img1 = (const float*)d_in[0];
    const float* img2 = (const float*)d_in[1];
    const float* win  = (const float*)d_in[2];
    float* out = (float*)d_out;
    float* partial = (float*)d_ws;

    dim3 grid(NGX, NGY, NCH);            // 10 x 8 x 48 = 3840 blocks (1 wave each)
    dim3 block(64);

    ssim_fused_kernel<<<grid, block, 0, stream>>>(img1, img2, win, partial);

    const int nblocks = NGX * NGY * NCH; // 3840, divisible by 4
    const double inv_count = 1.0 / ((double)NCH * OW * OH);
    reduce_partials_kernel<<<1, 256, 0, stream>>>(partial, nblocks / 4, out, inv_count);
}